// Round 8
// baseline (192.127 us; speedup 1.0000x reference)
//
#include <hip/hip_runtime.h>
#include <math.h>

#define NRAYS 8192
#define T 128
#define H 128
#define SHD 16
#define RPL 4                      // rays per block (looped)
#define NBLK (NRAYS / RPL)

using short8 = __attribute__((ext_vector_type(8))) short;
using f32x4  = __attribute__((ext_vector_type(4))) float;
using f32x2  = __attribute__((ext_vector_type(2))) float;
using u32x2  = __attribute__((ext_vector_type(2))) unsigned;

__device__ __forceinline__ float fexp(float x) {
  return exp2f(x * 1.44269504088896341f);
}
__device__ __forceinline__ float softplus_f(float x) {
  return fmaxf(x, 0.f) + 0.693147180559945309f * log2f(1.f + fexp(-fabsf(x)));
}
__device__ __forceinline__ float sigmoid_f(float x) {
  return __builtin_amdgcn_rcpf(1.f + fexp(-x));
}

// RNE float->bf16 (preprocess only)
__device__ __forceinline__ unsigned f2bf(float f) {
  unsigned u = __float_as_uint(f);
  return (u + 0x7fffu + ((u >> 16) & 1u)) >> 16;
}

// round-half-up bf16 pack of a float pair: v_pk_add_u32 + v_perm (2 VALU)
__device__ __forceinline__ unsigned pk2(f32x2 h) {
  const u32x2 u = __builtin_bit_cast(u32x2, h) + (u32x2){0x8000u, 0x8000u};
  return __builtin_amdgcn_perm(u[1], u[0], 0x07060302u);
}

// async global->LDS DMA, 16B per lane (wave-uniform LDS base + lane*16)
__device__ __forceinline__ void gload_lds16(const void* g, void* l) {
  __builtin_amdgcn_global_load_lds(
      (const __attribute__((address_space(1))) unsigned*)g,
      (__attribute__((address_space(3))) unsigned*)l, 16, 0, 0);
}

// ---- preprocess ----
// w2t: bf16 W2^T, XOR-swizzled: w2t[n*128 + p], octet o=(p>>3)^(n&7), k=o*8+(p&7)
//      holds W2[k][n]  -> conflict-free ds_read_b128 A-frag pattern (R3/R5-verified)
// woutf[(kk*64+L)*8+j]: epilogue A-frag A[m=c][k=kk*32+g*8+j]:
//   m=0 -> Wd, m=1..3 -> Wc[:,m-1], m>=4 -> 0   (L = g*16+c)
__global__ void preprocess(const float* __restrict__ W2, const float* __restrict__ Wd,
                           const float* __restrict__ Wc,
                           unsigned short* __restrict__ w2t,
                           unsigned short* __restrict__ woutf) {
  const int t = blockIdx.x * 256 + threadIdx.x;
  if (t < 16384) {
    const int n = t >> 7, p = t & 127;
    const int o = (p >> 3) ^ (n & 7);
    const int k = o * 8 + (p & 7);
    w2t[t] = (unsigned short)f2bf(W2[k * 128 + n]);
  }
  if (t < 2048) {
    const int kk = t >> 9, L = (t >> 3) & 63, j = t & 7;
    const int c = L & 15, g = L >> 4;
    const int k = kk * 32 + g * 8 + j;
    float v = 0.f;
    if (c == 0) v = Wd[k];
    else if (c < 4) v = Wc[k * 3 + (c - 1)];
    woutf[t] = (unsigned short)f2bf(v);
  }
}

// 4 rays per block (looped), W2 staged once. Wave w owns samples [32w, 32w+32).
__global__ __launch_bounds__(256, 4) void nerf_render(
    const float* __restrict__ origins, const float* __restrict__ dirs,
    const float* __restrict__ u, const float* __restrict__ W1,
    const float* __restrict__ b1, const float* __restrict__ b2,
    const float* __restrict__ bd, const float* __restrict__ Wc,
    const float* __restrict__ bc, const unsigned short* __restrict__ w2t,
    const unsigned short* __restrict__ woutf, float* __restrict__ out)
{
  const int tid = threadIdx.x;
  const int L = tid & 63;
  const int w = tid >> 6;
  const int g = L >> 4;
  const int c = L & 15;

  __shared__ __align__(16) short Bs[16384];       // swizzled W2^T, persistent across rays
  __shared__ __align__(16) short As2[4 * 640];    // per-wave epilogue slab; head aliased as SredA
  __shared__ __align__(16) float baseA[H];        // affine layer-1 SoA (per ray)
  __shared__ __align__(16) float slopeA[H];
  __shared__ float ts_s[T];
  __shared__ float mask_s[T];
  __shared__ float rayp[8];                       // {tfar_c, dnorm, active, cpoff0..2}
  __shared__ float wred[2][4];
  __shared__ float wtot[2];

  // ---- stage W2 once: async DMA, 16B/lane, wave-uniform base + lane*16 ----
  #pragma unroll
  for (int i = 0; i < 8; ++i) {
    const int idx = (i * 256 + tid) * 8;          // shorts; *16 bytes per lane-chunk
    gload_lds16(&w2t[idx], &Bs[idx]);
  }

  for (int rr = 0; rr < RPL; ++rr) {
    const int ray = blockIdx.x * RPL + rr;

    // ---- per-sample / per-ray setup (tid<128); SH on tid==128 ----
    if (tid < T) {
      const int tl = tid;
      const float ox = origins[ray*3+0], oy = origins[ray*3+1], oz = origins[ray*3+2];
      const float dx = dirs[ray*3+0],  dy = dirs[ray*3+1],  dz = dirs[ray*3+2];
      const float ix = 1.f/dx, iy = 1.f/dy, iz = 1.f/dz;
      const float t1x = (-1.f-ox)*ix, t2x = (1.f-ox)*ix;
      const float t1y = (-1.f-oy)*iy, t2y = (1.f-oy)*iy;
      const float t1z = (-1.f-oz)*iz, t2z = (1.f-oz)*iz;
      float tnear = fmaxf(fmaxf(fminf(t1x,t2x), fminf(t1y,t2y)), fminf(t1z,t2z));
      tnear = fmaxf(tnear, 0.f);
      const float tfar = fminf(fminf(fmaxf(t1x,t2x), fmaxf(t1y,t2y)), fmaxf(t1z,t2z));
      const bool  active = tfar > tnear;
      const float tfar_c = fmaxf(tfar, tnear + 1e-3f);
      const float ut = u[ray*T + tl];
      const float frac = ((float)tl + ut) * (1.f/(float)T);
      const float tt = tnear + (tfar_c - tnear) * frac;
      const float px = fmaf(dx, tt, ox);
      const float py = fmaf(dy, tt, oy);
      const float pz = fmaf(dz, tt, oz);
      ts_s[tl] = tt;
      const bool m = (fabsf(px) <= 1.f) && (fabsf(py) <= 1.f) && (fabsf(pz) <= 1.f) && active;
      mask_s[tl] = m ? 1.f : 0.f;
      const float w0 = W1[tl], w1v = W1[H + tl], w2v = W1[2*H + tl];
      baseA[tl]  = fmaf(ox, w0, fmaf(oy, w1v, fmaf(oz, w2v, b1[tl])));
      slopeA[tl] = fmaf(dx, w0, fmaf(dy, w1v, dz * w2v));
      if (tl == 0) {
        rayp[0] = tfar_c;
        rayp[1] = sqrtf(dx*dx + dy*dy + dz*dz);
        rayp[2] = active ? 1.f : 0.f;
      }
    } else if (tid == 128) {
      const float dx = dirs[ray*3+0], dy = dirs[ray*3+1], dz = dirs[ray*3+2];
      const float dnorm = sqrtf(dx*dx + dy*dy + dz*dz);
      const float nx = dx/dnorm, ny = dy/dnorm, nz = dz/dnorm;
      const float x2 = nx*nx, y2 = ny*ny, z2 = nz*nz;
      const float xy = nx*ny, yz = ny*nz, xz = nx*nz;
      float ynm[16];
      ynm[0]  = 0.282094791773878f;
      ynm[1]  = -0.48860251190292f*ny;
      ynm[2]  = 0.48860251190292f*nz;
      ynm[3]  = -0.48860251190292f*nx;
      ynm[4]  = 1.0925484305920792f*xy;
      ynm[5]  = -1.0925484305920792f*yz;
      ynm[6]  = 0.94617469575756f*z2 - 0.31539156525252f;
      ynm[7]  = -1.0925484305920792f*xz;
      ynm[8]  = 0.5462742152960396f*(x2-y2);
      ynm[9]  = 0.5900435899266435f*ny*(-3.f*x2+y2);
      ynm[10] = 2.8906114426405538f*xy*nz;
      ynm[11] = 0.4570457994644658f*ny*(1.f-5.f*z2);
      ynm[12] = 0.3731763325901154f*nz*(5.f*z2-3.f);
      ynm[13] = 0.4570457994644658f*nx*(1.f-5.f*z2);
      ynm[14] = 1.445305721320277f*nz*(x2-y2);
      ynm[15] = 0.5900435899266435f*nx*(-x2+3.f*y2);
      float cp0 = bc[0], cp1 = bc[1], cp2 = bc[2];
      #pragma unroll
      for (int s = 0; s < SHD; ++s) {
        cp0 = fmaf(ynm[s], Wc[(H+s)*3+0], cp0);
        cp1 = fmaf(ynm[s], Wc[(H+s)*3+1], cp1);
        cp2 = fmaf(ynm[s], Wc[(H+s)*3+2], cp2);
      }
      rayp[3] = cp0; rayp[4] = cp1; rayp[5] = cp2;
    }

    // ---- acc init = b2 (uniform, scalarized) ----
    f32x4 acc[2][8];
    #pragma unroll
    for (int mt = 0; mt < 8; ++mt) {
      const float4 bv = *(const float4*)&b2[mt*16 + g*4];
      #pragma unroll
      for (int tm = 0; tm < 2; ++tm) {
        acc[tm][mt][0] = bv.x; acc[tm][mt][1] = bv.y;
        acc[tm][mt][2] = bv.z; acc[tm][mt][3] = bv.w;
      }
    }
    __syncthreads();   // B1: setup visible; (rr==0) staging DMA drained

    // ---- fused affine-layer1 (packed VALU) + layer2 (MFMA, W2 from LDS) ----
    const float t0 = ts_s[32*w + c];
    const float t1 = ts_s[32*w + 16 + c];
    const f32x2 tz0 = {t0, t0}, tz1 = {t1, t1};
    const f32x2 zero2 = {0.f, 0.f};

    #pragma unroll
    for (int ks = 0; ks < 4; ++ks) {
      const int kb = ks*32 + g*8;
      const f32x4 bq0 = *(const f32x4*)&baseA[kb];
      const f32x4 bq1 = *(const f32x4*)&baseA[kb+4];
      const f32x4 sq0 = *(const f32x4*)&slopeA[kb];
      const f32x4 sq1 = *(const f32x4*)&slopeA[kb+4];
      const f32x2 b01 = {bq0[0], bq0[1]}, b23 = {bq0[2], bq0[3]};
      const f32x2 b45 = {bq1[0], bq1[1]}, b67 = {bq1[2], bq1[3]};
      const f32x2 s01 = {sq0[0], sq0[1]}, s23 = {sq0[2], sq0[3]};
      const f32x2 s45 = {sq1[0], sq1[1]}, s67 = {sq1[2], sq1[3]};
      const f32x2 a01 = __builtin_elementwise_max(__builtin_elementwise_fma(tz0, s01, b01), zero2);
      const f32x2 a23 = __builtin_elementwise_max(__builtin_elementwise_fma(tz0, s23, b23), zero2);
      const f32x2 a45 = __builtin_elementwise_max(__builtin_elementwise_fma(tz0, s45, b45), zero2);
      const f32x2 a67 = __builtin_elementwise_max(__builtin_elementwise_fma(tz0, s67, b67), zero2);
      const f32x2 e01 = __builtin_elementwise_max(__builtin_elementwise_fma(tz1, s01, b01), zero2);
      const f32x2 e23 = __builtin_elementwise_max(__builtin_elementwise_fma(tz1, s23, b23), zero2);
      const f32x2 e45 = __builtin_elementwise_max(__builtin_elementwise_fma(tz1, s45, b45), zero2);
      const f32x2 e67 = __builtin_elementwise_max(__builtin_elementwise_fma(tz1, s67, b67), zero2);
      union U { uint4 u; short8 s; } A0, A1;
      A0.u = make_uint4(pk2(a01), pk2(a23), pk2(a45), pk2(a67));
      A1.u = make_uint4(pk2(e01), pk2(e23), pk2(e45), pk2(e67));
      const int swb = ((ks*4 + g) ^ (c & 7)) * 8;
      #pragma unroll
      for (int mt = 0; mt < 8; ++mt) {
        const short8 wf = *(const short8*)&Bs[(mt*16 + c)*128 + swb];
        acc[0][mt] = __builtin_amdgcn_mfma_f32_16x16x32_bf16(wf, A0.s, acc[0][mt], 0, 0, 0);
        acc[1][mt] = __builtin_amdgcn_mfma_f32_16x16x32_bf16(wf, A1.s, acc[1][mt], 0, 0, 0);
      }
    }

    // ---- epilogue: relu -> bf16 slab (per-wave private) -> MFMA dot with Wout ----
    short* As2w = As2 + w * 640;
    short8 wa[4];
    #pragma unroll
    for (int kk = 0; kk < 4; ++kk)
      wa[kk] = *(const short8*)&woutf[(kk*64 + L)*8];   // global, L2-hot

    f32x4 osig[2];
    #pragma unroll
    for (int tm = 0; tm < 2; ++tm) {
      f32x4 oacc;
      oacc[0] = 0.f; oacc[1] = 0.f; oacc[2] = 0.f; oacc[3] = 0.f;
      #pragma unroll
      for (int kk = 0; kk < 4; ++kk) {
        const f32x2 zz = {0.f, 0.f};
        #pragma unroll
        for (int i = 0; i < 2; ++i) {
          const f32x4 a = acc[tm][kk*2 + i];
          const f32x2 h01 = __builtin_elementwise_max((f32x2){a[0], a[1]}, zz);
          const f32x2 h23 = __builtin_elementwise_max((f32x2){a[2], a[3]}, zz);
          *(uint2*)&As2w[c*40 + i*16 + g*4] = make_uint2(pk2(h01), pk2(h23));
        }
        const short8 hbf = *(const short8*)&As2w[c*40 + g*8];
        oacc = __builtin_amdgcn_mfma_f32_16x16x32_bf16(wa[kk], hbf, oacc, 0, 0, 0);
      }
      osig[tm] = oacc;
    }
    __syncthreads();   // B2: all As2 slab reads done -> safe to alias SredA
    float4* SredA = (float4*)As2;   // [128] {sigma_pre, cp0, cp1, cp2}
    if (g == 0) {
      #pragma unroll
      for (int tm = 0; tm < 2; ++tm)
        SredA[32*w + 16*tm + c] = make_float4(osig[tm][0], osig[tm][1], osig[tm][2], osig[tm][3]);
    }
    __syncthreads();   // B3: SredA visible

    // ---- per-sample activations + transmittance (tid<128) ----
    float sd = 0.f, cc0 = 0.f, cc1 = 0.f, cc2 = 0.f;
    if (tid < T) {
      const float4 sv = SredA[tid];
      const float mk = mask_s[tid];
      const float sigma = softplus_f(sv.x + bd[0]) * mk;
      cc0 = mk * sigmoid_f(sv.y + rayp[3]);
      cc1 = mk * sigmoid_f(sv.z + rayp[4]);
      cc2 = mk * sigmoid_f(sv.w + rayp[5]);
      const float tt = ts_s[tid];
      const float tnext = (tid < T-1) ? ts_s[tid + 1] : rayp[0] * 10.f;
      sd = sigma * (tnext - tt) * rayp[1];
    }

    // ---- inclusive scan: in-wave shfl + cross-wave stitch ----
    float val = sd;
    #pragma unroll
    for (int off = 1; off < 64; off <<= 1) {
      const float tmp = __shfl_up(val, off);
      if (L >= off) val += tmp;
    }
    if (tid < T && L == 63) wtot[w] = val;
    __syncthreads();   // B4
    const float csum = val + ((w == 1) ? wtot[0] : 0.f);

    // ---- weights + per-ray reduction ----
    float wgt = 0.f, wcx = 0.f, wcy = 0.f, wcz = 0.f;
    if (tid < T) {
      wgt = fexp(sd - csum) - fexp(-csum);
      wcx = wgt * cc0; wcy = wgt * cc1; wcz = wgt * cc2;
    }
    #pragma unroll
    for (int mm = 32; mm >= 1; mm >>= 1) {
      wgt += __shfl_xor(wgt, mm);
      wcx += __shfl_xor(wcx, mm);
      wcy += __shfl_xor(wcy, mm);
      wcz += __shfl_xor(wcz, mm);
    }
    if (tid < T && L == 0) {
      wred[w][0] = wgt; wred[w][1] = wcx; wred[w][2] = wcy; wred[w][3] = wcz;
    }
    __syncthreads();   // B5
    if (tid == 0) {
      const float aw = wred[0][0] + wred[1][0];
      const float o0 = wred[0][1] + wred[1][1];
      const float o1 = wred[0][2] + wred[1][2];
      const float o2 = wred[0][3] + wred[1][3];
      const bool act = rayp[2] != 0.f;
      out[ray*4+0] = act ? o0 : 0.f;
      out[ray*4+1] = act ? o1 : 0.f;
      out[ray*4+2] = act ? o2 : 0.f;
      out[ray*4+3] = act ? aw : 0.f;
    }
    __syncthreads();   // B6: rayp/wred consumed; next ray may overwrite setup state
  }
}

extern "C" void kernel_launch(void* const* d_in, const int* in_sizes, int n_in,
                              void* d_out, int out_size, void* d_ws, size_t ws_size,
                              hipStream_t stream) {
  const float* origins = (const float*)d_in[0];
  const float* dirs    = (const float*)d_in[1];
  const float* u       = (const float*)d_in[2];
  const float* W1      = (const float*)d_in[3];
  const float* b1      = (const float*)d_in[4];
  const float* W2      = (const float*)d_in[5];
  const float* b2      = (const float*)d_in[6];
  const float* Wd      = (const float*)d_in[7];
  const float* bd      = (const float*)d_in[8];
  const float* Wc      = (const float*)d_in[9];
  const float* bc      = (const float*)d_in[10];

  unsigned short* w2t   = (unsigned short*)d_ws;
  unsigned short* woutf = (unsigned short*)((char*)d_ws + 32768);

  preprocess<<<64, 256, 0, stream>>>(W2, Wd, Wc, w2t, woutf);
  nerf_render<<<NBLK, 256, 0, stream>>>(origins, dirs, u, W1, b1, b2, bd, Wc, bc,
                                        w2t, woutf, (float*)d_out);
}

// Round 9
// 132.115 us; speedup vs baseline: 1.4542x; 1.4542x over previous
//
#include <hip/hip_runtime.h>
#include <math.h>

#define NRAYS 8192
#define T 128
#define H 128
#define SHD 16

using short8 = __attribute__((ext_vector_type(8))) short;
using f32x4  = __attribute__((ext_vector_type(4))) float;
using f32x2  = __attribute__((ext_vector_type(2))) float;
using u32x2  = __attribute__((ext_vector_type(2))) unsigned;

__device__ __forceinline__ float fexp(float x) {
  return exp2f(x * 1.44269504088896341f);
}
__device__ __forceinline__ float softplus_f(float x) {
  return fmaxf(x, 0.f) + 0.693147180559945309f * log2f(1.f + fexp(-fabsf(x)));
}
__device__ __forceinline__ float sigmoid_f(float x) {
  return __builtin_amdgcn_rcpf(1.f + fexp(-x));
}

// RNE float->bf16 (preprocess only)
__device__ __forceinline__ unsigned f2bf(float f) {
  unsigned u = __float_as_uint(f);
  return (u + 0x7fffu + ((u >> 16) & 1u)) >> 16;
}

// round-half-up bf16 pack of a float pair: v_pk_add_u32 + v_perm (2 VALU)
__device__ __forceinline__ unsigned pk2(f32x2 h) {
  const u32x2 u = __builtin_bit_cast(u32x2, h) + (u32x2){0x8000u, 0x8000u};
  return __builtin_amdgcn_perm(u[1], u[0], 0x07060302u);
}

// ---- preprocess ----
// w2t: bf16 W2^T, XOR-swizzled: w2t[n*128 + p], octet o=(p>>3)^(n&7), k=o*8+(p&7)
//      holds W2[k][n]  -> conflict-free ds_read_b128 A-frag pattern (R3/R5-verified)
// woutf[(kk*64+L)*8+j]: epilogue A-frag A[m=c][k=kk*32+g*8+j]:
//   m=0 -> Wd, m=1..3 -> Wc[:,m-1], m>=4 -> 0   (L = g*16+c)
// rayp_all[r][8] = {tfar_c, dnorm, active, cp0, cp1, cp2, tnear, 0}  (AABB + SH)
__global__ void preprocess(const float* __restrict__ W2, const float* __restrict__ Wd,
                           const float* __restrict__ Wc, const float* __restrict__ bc,
                           const float* __restrict__ origins, const float* __restrict__ dirs,
                           unsigned short* __restrict__ w2t,
                           unsigned short* __restrict__ woutf,
                           float* __restrict__ rayp_all) {
  const int t = blockIdx.x * 256 + threadIdx.x;
  if (t < 16384) {
    const int n = t >> 7, p = t & 127;
    const int o = (p >> 3) ^ (n & 7);
    const int k = o * 8 + (p & 7);
    w2t[t] = (unsigned short)f2bf(W2[k * 128 + n]);
  }
  if (t < 2048) {
    const int kk = t >> 9, L = (t >> 3) & 63, j = t & 7;
    const int c = L & 15, g = L >> 4;
    const int k = kk * 32 + g * 8 + j;
    float v = 0.f;
    if (c == 0) v = Wd[k];
    else if (c < 4) v = Wc[k * 3 + (c - 1)];
    woutf[t] = (unsigned short)f2bf(v);
  }
  if (t < NRAYS) {
    const float ox = origins[t*3+0], oy = origins[t*3+1], oz = origins[t*3+2];
    const float dx = dirs[t*3+0],  dy = dirs[t*3+1],  dz = dirs[t*3+2];
    const float ix = 1.f/dx, iy = 1.f/dy, iz = 1.f/dz;
    const float t1x = (-1.f-ox)*ix, t2x = (1.f-ox)*ix;
    const float t1y = (-1.f-oy)*iy, t2y = (1.f-oy)*iy;
    const float t1z = (-1.f-oz)*iz, t2z = (1.f-oz)*iz;
    float tnear = fmaxf(fmaxf(fminf(t1x,t2x), fminf(t1y,t2y)), fminf(t1z,t2z));
    tnear = fmaxf(tnear, 0.f);
    const float tfar = fminf(fminf(fmaxf(t1x,t2x), fmaxf(t1y,t2y)), fmaxf(t1z,t2z));
    const bool  active = tfar > tnear;
    const float tfar_c = fmaxf(tfar, tnear + 1e-3f);
    const float dnorm = sqrtf(dx*dx + dy*dy + dz*dz);
    const float nx = dx/dnorm, ny = dy/dnorm, nz = dz/dnorm;
    const float x2 = nx*nx, y2 = ny*ny, z2 = nz*nz;
    const float xy = nx*ny, yz = ny*nz, xz = nx*nz;
    float ynm[16];
    ynm[0]  = 0.282094791773878f;
    ynm[1]  = -0.48860251190292f*ny;
    ynm[2]  = 0.48860251190292f*nz;
    ynm[3]  = -0.48860251190292f*nx;
    ynm[4]  = 1.0925484305920792f*xy;
    ynm[5]  = -1.0925484305920792f*yz;
    ynm[6]  = 0.94617469575756f*z2 - 0.31539156525252f;
    ynm[7]  = -1.0925484305920792f*xz;
    ynm[8]  = 0.5462742152960396f*(x2-y2);
    ynm[9]  = 0.5900435899266435f*ny*(-3.f*x2+y2);
    ynm[10] = 2.8906114426405538f*xy*nz;
    ynm[11] = 0.4570457994644658f*ny*(1.f-5.f*z2);
    ynm[12] = 0.3731763325901154f*nz*(5.f*z2-3.f);
    ynm[13] = 0.4570457994644658f*nx*(1.f-5.f*z2);
    ynm[14] = 1.445305721320277f*nz*(x2-y2);
    ynm[15] = 0.5900435899266435f*nx*(-x2+3.f*y2);
    float cp0 = bc[0], cp1 = bc[1], cp2 = bc[2];
    #pragma unroll
    for (int s = 0; s < SHD; ++s) {
      cp0 = fmaf(ynm[s], Wc[(H+s)*3+0], cp0);
      cp1 = fmaf(ynm[s], Wc[(H+s)*3+1], cp1);
      cp2 = fmaf(ynm[s], Wc[(H+s)*3+2], cp2);
    }
    rayp_all[t*8+0] = tfar_c;
    rayp_all[t*8+1] = dnorm;
    rayp_all[t*8+2] = active ? 1.f : 0.f;
    rayp_all[t*8+3] = cp0;
    rayp_all[t*8+4] = cp1;
    rayp_all[t*8+5] = cp2;
    rayp_all[t*8+6] = tnear;
    rayp_all[t*8+7] = 0.f;
  }
}

// One ray per block; wave w owns samples [32w, 32w+32): acc = 64 AGPRs.
__global__ __launch_bounds__(256, 4) void nerf_render(
    const float* __restrict__ origins, const float* __restrict__ dirs,
    const float* __restrict__ u, const float* __restrict__ W1,
    const float* __restrict__ b1, const float* __restrict__ b2,
    const float* __restrict__ bd, const unsigned short* __restrict__ w2t,
    const unsigned short* __restrict__ woutf, const float* __restrict__ rayp_all,
    float* __restrict__ out)
{
  const int ray = blockIdx.x;
  const int tid = threadIdx.x;
  const int L = tid & 63;
  const int w = tid >> 6;
  const int g = L >> 4;
  const int c = L & 15;

  __shared__ __align__(16) short Bs[16384];       // swizzled W2^T; head aliased as SredP later
  __shared__ __align__(16) short As2[4 * 640];    // per-wave epilogue slab
  __shared__ __align__(16) float baseA[H];        // affine layer-1 SoA
  __shared__ __align__(16) float slopeA[H];
  __shared__ float ts_s[T];
  __shared__ float mask_s[T];
  __shared__ float wred[2][4];
  __shared__ float wtot[2];

  // per-ray scalars (wave-uniform -> scalar loads; written by preprocess)
  const float tfar_c = rayp_all[ray*8+0];
  const float dnorm  = rayp_all[ray*8+1];
  const float actf   = rayp_all[ray*8+2];
  const float cpo0   = rayp_all[ray*8+3];
  const float cpo1   = rayp_all[ray*8+4];
  const float cpo2   = rayp_all[ray*8+5];
  const float tnear  = rayp_all[ray*8+6];

  // ---- stage W2 (LDS), R7-proven float4 path ----
  {
    const float4* src = (const float4*)w2t;
    float4* dst = (float4*)Bs;
    #pragma unroll
    for (int i = 0; i < 8; ++i) dst[tid + i * 256] = src[tid + i * 256];
  }

  // ---- per-sample setup (tid<128): samples + affine layer-1 coefficients ----
  if (tid < T) {
    const int tl = tid;
    const float ox = origins[ray*3+0], oy = origins[ray*3+1], oz = origins[ray*3+2];
    const float dx = dirs[ray*3+0],  dy = dirs[ray*3+1],  dz = dirs[ray*3+2];
    const bool active = actf != 0.f;
    const float ut = u[ray*T + tl];
    const float frac = ((float)tl + ut) * (1.f/(float)T);
    const float tt = tnear + (tfar_c - tnear) * frac;
    const float px = fmaf(dx, tt, ox);
    const float py = fmaf(dy, tt, oy);
    const float pz = fmaf(dz, tt, oz);
    ts_s[tl] = tt;
    const bool m = (fabsf(px) <= 1.f) && (fabsf(py) <= 1.f) && (fabsf(pz) <= 1.f) && active;
    mask_s[tl] = m ? 1.f : 0.f;
    const float w0 = W1[tl], w1v = W1[H + tl], w2v = W1[2*H + tl];
    baseA[tl]  = fmaf(ox, w0, fmaf(oy, w1v, fmaf(oz, w2v, b1[tl])));
    slopeA[tl] = fmaf(dx, w0, fmaf(dy, w1v, dz * w2v));
  }

  // ---- acc init = b2 (uniform global reads, L2-hot) ----
  f32x4 acc[2][8];
  #pragma unroll
  for (int mt = 0; mt < 8; ++mt) {
    const float4 bv = *(const float4*)&b2[mt*16 + g*4];
    #pragma unroll
    for (int tm = 0; tm < 2; ++tm) {
      acc[tm][mt][0] = bv.x; acc[tm][mt][1] = bv.y;
      acc[tm][mt][2] = bv.z; acc[tm][mt][3] = bv.w;
    }
  }
  __syncthreads();

  // ---- fused affine-layer1 (packed VALU) + layer2 (MFMA, W2 frags from LDS) ----
  const float t0 = ts_s[32*w + c];
  const float t1 = ts_s[32*w + 16 + c];
  const f32x2 tz0 = {t0, t0}, tz1 = {t1, t1};
  const f32x2 zero2 = {0.f, 0.f};

  #pragma unroll
  for (int ks = 0; ks < 4; ++ks) {
    const int kb = ks*32 + g*8;
    const f32x4 bq0 = *(const f32x4*)&baseA[kb];
    const f32x4 bq1 = *(const f32x4*)&baseA[kb+4];
    const f32x4 sq0 = *(const f32x4*)&slopeA[kb];
    const f32x4 sq1 = *(const f32x4*)&slopeA[kb+4];
    const f32x2 b01 = {bq0[0], bq0[1]}, b23 = {bq0[2], bq0[3]};
    const f32x2 b45 = {bq1[0], bq1[1]}, b67 = {bq1[2], bq1[3]};
    const f32x2 s01 = {sq0[0], sq0[1]}, s23 = {sq0[2], sq0[3]};
    const f32x2 s45 = {sq1[0], sq1[1]}, s67 = {sq1[2], sq1[3]};
    const f32x2 a01 = __builtin_elementwise_max(__builtin_elementwise_fma(tz0, s01, b01), zero2);
    const f32x2 a23 = __builtin_elementwise_max(__builtin_elementwise_fma(tz0, s23, b23), zero2);
    const f32x2 a45 = __builtin_elementwise_max(__builtin_elementwise_fma(tz0, s45, b45), zero2);
    const f32x2 a67 = __builtin_elementwise_max(__builtin_elementwise_fma(tz0, s67, b67), zero2);
    const f32x2 e01 = __builtin_elementwise_max(__builtin_elementwise_fma(tz1, s01, b01), zero2);
    const f32x2 e23 = __builtin_elementwise_max(__builtin_elementwise_fma(tz1, s23, b23), zero2);
    const f32x2 e45 = __builtin_elementwise_max(__builtin_elementwise_fma(tz1, s45, b45), zero2);
    const f32x2 e67 = __builtin_elementwise_max(__builtin_elementwise_fma(tz1, s67, b67), zero2);
    union U { uint4 u; short8 s; } A0, A1;
    A0.u = make_uint4(pk2(a01), pk2(a23), pk2(a45), pk2(a67));
    A1.u = make_uint4(pk2(e01), pk2(e23), pk2(e45), pk2(e67));
    const int swb = ((ks*4 + g) ^ (c & 7)) * 8;   // swizzled octet (conflict-free)
    #pragma unroll
    for (int mt = 0; mt < 8; ++mt) {
      const short8 wf = *(const short8*)&Bs[(mt*16 + c)*128 + swb];
      acc[0][mt] = __builtin_amdgcn_mfma_f32_16x16x32_bf16(wf, A0.s, acc[0][mt], 0, 0, 0);
      acc[1][mt] = __builtin_amdgcn_mfma_f32_16x16x32_bf16(wf, A1.s, acc[1][mt], 0, 0, 0);
    }
  }
  __syncthreads();   // all waves done with Bs -> safe to alias SredP onto it
  float4* SredP = (float4*)Bs;   // [128] float4 {sigma_pre, cp0, cp1, cp2}

  // ---- epilogue: relu -> bf16 slab -> 4-k-step MFMA dot with Wout ----
  short* As2w = As2 + w * 640;
  short8 wa[4];
  #pragma unroll
  for (int kk = 0; kk < 4; ++kk)
    wa[kk] = *(const short8*)&woutf[(kk*64 + L)*8];   // global, L2-hot

  #pragma unroll
  for (int tm = 0; tm < 2; ++tm) {
    f32x4 oacc;
    oacc[0] = 0.f; oacc[1] = 0.f; oacc[2] = 0.f; oacc[3] = 0.f;
    #pragma unroll
    for (int kk = 0; kk < 4; ++kk) {
      #pragma unroll
      for (int i = 0; i < 2; ++i) {
        const f32x4 a = acc[tm][kk*2 + i];
        const f32x2 h01 = __builtin_elementwise_max((f32x2){a[0], a[1]}, zero2);
        const f32x2 h23 = __builtin_elementwise_max((f32x2){a[2], a[3]}, zero2);
        *(uint2*)&As2w[c*40 + i*16 + g*4] = make_uint2(pk2(h01), pk2(h23));
      }
      const short8 hbf = *(const short8*)&As2w[c*40 + g*8];
      oacc = __builtin_amdgcn_mfma_f32_16x16x32_bf16(wa[kk], hbf, oacc, 0, 0, 0);
    }
    if (g == 0)   // lane holds {sigma,c0,c1,c2} for sample 32w+16tm+c
      SredP[32*w + 16*tm + c] = make_float4(oacc[0], oacc[1], oacc[2], oacc[3]);
  }
  __syncthreads();

  // ---- per-sample activations + transmittance (tid<128) ----
  float sd = 0.f, cc0 = 0.f, cc1 = 0.f, cc2 = 0.f;
  if (tid < T) {
    const float4 sv = SredP[tid];
    const float mk = mask_s[tid];
    const float sigma = softplus_f(sv.x + bd[0]) * mk;
    cc0 = mk * sigmoid_f(sv.y + cpo0);
    cc1 = mk * sigmoid_f(sv.z + cpo1);
    cc2 = mk * sigmoid_f(sv.w + cpo2);
    const float tt = ts_s[tid];
    const float tnext = (tid < T-1) ? ts_s[tid + 1] : tfar_c * 10.f;
    sd = sigma * (tnext - tt) * dnorm;
  }

  // ---- inclusive scan: in-wave shfl + cross-wave stitch ----
  float val = sd;
  #pragma unroll
  for (int off = 1; off < 64; off <<= 1) {
    const float tmp = __shfl_up(val, off);
    if (L >= off) val += tmp;
  }
  if (tid < T && L == 63) wtot[w] = val;
  __syncthreads();
  const float csum = val + ((w == 1) ? wtot[0] : 0.f);

  // ---- weights + per-ray reduction ----
  float wgt = 0.f, wcx = 0.f, wcy = 0.f, wcz = 0.f;
  if (tid < T) {
    wgt = fexp(sd - csum) - fexp(-csum);
    wcx = wgt * cc0; wcy = wgt * cc1; wcz = wgt * cc2;
  }
  #pragma unroll
  for (int mm = 32; mm >= 1; mm >>= 1) {
    wgt += __shfl_xor(wgt, mm);
    wcx += __shfl_xor(wcx, mm);
    wcy += __shfl_xor(wcy, mm);
    wcz += __shfl_xor(wcz, mm);
  }
  if (tid < T && L == 0) {
    wred[w][0] = wgt; wred[w][1] = wcx; wred[w][2] = wcy; wred[w][3] = wcz;
  }
  __syncthreads();
  if (tid == 0) {
    const float aw = wred[0][0] + wred[1][0];
    const float o0 = wred[0][1] + wred[1][1];
    const float o1 = wred[0][2] + wred[1][2];
    const float o2 = wred[0][3] + wred[1][3];
    const bool act = actf != 0.f;
    out[ray*4+0] = act ? o0 : 0.f;
    out[ray*4+1] = act ? o1 : 0.f;
    out[ray*4+2] = act ? o2 : 0.f;
    out[ray*4+3] = act ? aw : 0.f;
  }
}

extern "C" void kernel_launch(void* const* d_in, const int* in_sizes, int n_in,
                              void* d_out, int out_size, void* d_ws, size_t ws_size,
                              hipStream_t stream) {
  const float* origins = (const float*)d_in[0];
  const float* dirs    = (const float*)d_in[1];
  const float* u       = (const float*)d_in[2];
  const float* W1      = (const float*)d_in[3];
  const float* b1      = (const float*)d_in[4];
  const float* W2      = (const float*)d_in[5];
  const float* b2      = (const float*)d_in[6];
  const float* Wd      = (const float*)d_in[7];
  const float* bd      = (const float*)d_in[8];
  const float* Wc      = (const float*)d_in[9];
  const float* bc      = (const float*)d_in[10];

  unsigned short* w2t      = (unsigned short*)d_ws;
  unsigned short* woutf    = (unsigned short*)((char*)d_ws + 32768);
  float*          rayp_all = (float*)((char*)d_ws + 36864);

  preprocess<<<64, 256, 0, stream>>>(W2, Wd, Wc, bc, origins, dirs,
                                     w2t, woutf, rayp_all);
  nerf_render<<<NRAYS, 256, 0, stream>>>(origins, dirs, u, W1, b1, b2, bd,
                                         w2t, woutf, rayp_all, (float*)d_out);
}